// Round 1
// baseline (311.531 us; speedup 1.0000x reference)
//
#include <hip/hip_runtime.h>
#include <math.h>

// ScatLayer: fused DTCWT-style scattering layer.
// x:(32,3,512,512) f32 -> Z:(32,21,256,256) f32
// Z[b, s*3+ch, i, j]: s=0 ll(2x2 avg), s=1..6 magnitudes of complex subbands
// from lh (d15,d165), hh (d45,d135), hl (d75,d105).
//
// Single fused kernel: LDS-staged input tile (+halo 3), horizontal h0/h1
// filters into LDS, vertical filters + q2c + magnitude in registers.
// Memory-bound: ~277 MB ideal traffic -> ~44 us floor @ 6.3 TB/s.

#define IMG   512
#define OUTD  256
#define TO_W  32            // output tile width
#define TO_H  16            // output tile height
#define IN_W  70            // 2*TO_W + 6 (halo 3 each side)
#define IN_H  38            // 2*TO_H + 6
#define IN_S  72            // s_in row stride (floats)
#define F_S   66            // s_lo/s_hi row stride (even -> 8B-aligned float2)

#define MAGBIAS  0.01f
#define MB2      (MAGBIAS*MAGBIAS)
#define RSQRT2   0.70710678118654752f

__global__ __launch_bounds__(256)
void scat_kernel(const float* __restrict__ x,
                 const float* __restrict__ gh0,
                 const float* __restrict__ gh1,
                 float* __restrict__ out)
{
    __shared__ float s_in[IN_H][IN_S];
    __shared__ float s_lo[IN_H][F_S];
    __shared__ float s_hi[IN_H][F_S];

    const int tid = threadIdx.x;
    const int tx  = blockIdx.x;      // 0..7   (output cols / 32)
    const int ty  = blockIdx.y;      // 0..15  (output rows / 16)
    const int img = blockIdx.z;      // 0..95  (b*3 + ch)
    const int b   = img / 3;
    const int ch  = img - 3 * b;

    // filters (symmetric; uniform loads -> scalar-cached)
    float h0[5], h1[7];
#pragma unroll
    for (int k = 0; k < 5; ++k) h0[k] = gh0[k];
#pragma unroll
    for (int k = 0; k < 7; ++k) h1[k] = gh1[k];

    const float* xin = x + (size_t)img * (IMG * IMG);
    const int row0 = ty * (2 * TO_H) - 3;   // global row of s_in row 0
    const int col0 = tx * (2 * TO_W) - 3;   // global col of s_in col 0

    // ---- phase 1: load input tile with symmetric padding ----
    for (int idx = tid; idx < IN_H * IN_W; idx += 256) {
        int r = idx / IN_W;
        int c = idx - r * IN_W;
        int gr = row0 + r;
        gr = (gr < 0) ? (-gr - 1) : ((gr >= IMG) ? (2 * IMG - 1 - gr) : gr);
        int gc = col0 + c;
        gc = (gc < 0) ? (-gc - 1) : ((gc >= IMG) ? (2 * IMG - 1 - gc) : gc);
        s_in[r][c] = xin[gr * IMG + gc];
    }
    __syncthreads();

    // ---- phase 2: horizontal filters (core 64 cols, all 38 rows) ----
    // lo[r][c] = sum_k h0[k] * x[col0+3+c + k-2]  -> s_in[r][c+1+k]
    // hi[r][c] = sum_k h1[k] * x[col0+3+c + k-3]  -> s_in[r][c+k]
    for (int idx = tid; idx < IN_H * 64; idx += 256) {
        int r = idx >> 6;
        int c = idx & 63;
        float lo = 0.f, hi = 0.f;
#pragma unroll
        for (int k = 0; k < 5; ++k) lo += h0[k] * s_in[r][c + 1 + k];
#pragma unroll
        for (int k = 0; k < 7; ++k) hi += h1[k] * s_in[r][c + k];
        s_lo[r][c] = lo;
        s_hi[r][c] = hi;
    }
    __syncthreads();

    // ---- phase 3: vertical filters + q2c + magnitude + ll pool ----
    const int j  = tid & 31;        // output col within tile
    const int i0 = tid >> 5;        // 0..7; handles rows i0 and i0+8
    const size_t pixplane = (size_t)OUTD * OUTD;
    const size_t obase = ((size_t)b * 21 + ch) * pixplane;   // s=0 slot
    const int gj = tx * TO_W + j;

#pragma unroll
    for (int p = 0; p < 2; ++p) {
        const int i  = i0 + p * 8;          // 0..15
        const int yy = 2 * i;               // s_lo row base (rows yy..yy+7)

        // lo path: ll (h0) + lh (h1)
        float2 v[8];
#pragma unroll
        for (int t = 0; t < 8; ++t)
            v[t] = *(const float2*)&s_lo[yy + t][2 * j];

        float lh00 = 0.f, lh01 = 0.f, lh10 = 0.f, lh11 = 0.f;
#pragma unroll
        for (int k = 0; k < 7; ++k) {
            lh00 += h1[k] * v[k].x;     lh01 += h1[k] * v[k].y;
            lh10 += h1[k] * v[k + 1].x; lh11 += h1[k] * v[k + 1].y;
        }
        float ll00 = 0.f, ll01 = 0.f, ll10 = 0.f, ll11 = 0.f;
#pragma unroll
        for (int k = 0; k < 5; ++k) {
            ll00 += h0[k] * v[k + 1].x; ll01 += h0[k] * v[k + 1].y;
            ll10 += h0[k] * v[k + 2].x; ll11 += h0[k] * v[k + 2].y;
        }

        // hi path: hl (h0) + hh (h1)
#pragma unroll
        for (int t = 0; t < 8; ++t)
            v[t] = *(const float2*)&s_hi[yy + t][2 * j];

        float hh00 = 0.f, hh01 = 0.f, hh10 = 0.f, hh11 = 0.f;
#pragma unroll
        for (int k = 0; k < 7; ++k) {
            hh00 += h1[k] * v[k].x;     hh01 += h1[k] * v[k].y;
            hh10 += h1[k] * v[k + 1].x; hh11 += h1[k] * v[k + 1].y;
        }
        float hl00 = 0.f, hl01 = 0.f, hl10 = 0.f, hl11 = 0.f;
#pragma unroll
        for (int k = 0; k < 5; ++k) {
            hl00 += h0[k] * v[k + 1].x; hl01 += h0[k] * v[k + 1].y;
            hl10 += h0[k] * v[k + 2].x; hl11 += h0[k] * v[k + 2].y;
        }

        const int gi = ty * TO_H + i;
        const size_t pix = (size_t)gi * OUTD + gj;

        // s=0: ll 2x2 average pool
        out[obase + pix] = 0.25f * (ll00 + ll01 + ll10 + ll11);

        // q2c: a=(2i,2j) b=(2i,2j+1) c=(2i+1,2j) d=(2i+1,2j+1), scaled 1/sqrt2
        // band1: (a-d, b+c)   band2: (a+d, b-c)
        {   // lh -> d15 (s=1), d165 (s=6)
            float a = lh00 * RSQRT2, bq = lh01 * RSQRT2;
            float c = lh10 * RSQRT2, d  = lh11 * RSQRT2;
            float r1 = a - d, i1 = bq + c;
            float r2 = a + d, i2 = bq - c;
            out[obase + 1 * 3 * pixplane + pix] = sqrtf(r1 * r1 + i1 * i1 + MB2) - MAGBIAS;
            out[obase + 6 * 3 * pixplane + pix] = sqrtf(r2 * r2 + i2 * i2 + MB2) - MAGBIAS;
        }
        {   // hh -> d45 (s=2), d135 (s=5)
            float a = hh00 * RSQRT2, bq = hh01 * RSQRT2;
            float c = hh10 * RSQRT2, d  = hh11 * RSQRT2;
            float r1 = a - d, i1 = bq + c;
            float r2 = a + d, i2 = bq - c;
            out[obase + 2 * 3 * pixplane + pix] = sqrtf(r1 * r1 + i1 * i1 + MB2) - MAGBIAS;
            out[obase + 5 * 3 * pixplane + pix] = sqrtf(r2 * r2 + i2 * i2 + MB2) - MAGBIAS;
        }
        {   // hl -> d75 (s=3), d105 (s=4)
            float a = hl00 * RSQRT2, bq = hl01 * RSQRT2;
            float c = hl10 * RSQRT2, d  = hl11 * RSQRT2;
            float r1 = a - d, i1 = bq + c;
            float r2 = a + d, i2 = bq - c;
            out[obase + 3 * 3 * pixplane + pix] = sqrtf(r1 * r1 + i1 * i1 + MB2) - MAGBIAS;
            out[obase + 4 * 3 * pixplane + pix] = sqrtf(r2 * r2 + i2 * i2 + MB2) - MAGBIAS;
        }
    }
}

extern "C" void kernel_launch(void* const* d_in, const int* in_sizes, int n_in,
                              void* d_out, int out_size, void* d_ws, size_t ws_size,
                              hipStream_t stream) {
    const float* x   = (const float*)d_in[0];
    const float* h0  = (const float*)d_in[1];
    const float* h1  = (const float*)d_in[2];
    float* out = (float*)d_out;

    dim3 grid(IMG / (2 * TO_W), IMG / (2 * TO_H), 32 * 3);  // (8, 16, 96)
    dim3 block(256);
    hipLaunchKernelGGL(scat_kernel, grid, block, 0, stream, x, h0, h1, out);
}

// Round 2
// 272.094 us; speedup vs baseline: 1.1449x; 1.1449x over previous
//
#include <hip/hip_runtime.h>
#include <math.h>

// ScatLayer fused DTCWT scattering: x(32,3,512,512)f32 -> Z(32,21,256,256)f32.
// R1 restructure: register sliding-window vertical filter, on-the-fly
// horizontal filter from s_in (no s_lo/s_hi LDS round trip), float4 tile load.
// Tile: 32x32 outputs (64x64 input core), halo 4 left / 3 right / 3 top+bot.
// Each thread: 1 output column, 4 output rows (8-row register window, slide 2).

#define IMG   512
#define OUTD  256
#define TOW   32
#define TOH   32
#define INW   72            // = stride; col0 = tx*64 - 4 (16B-aligned)
#define INH   70            // row0 = ty*64 - 3
#define INS   72

#define MAGBIAS 0.01f
#define MB2     (MAGBIAS*MAGBIAS)

// horizontal filters at core cols (2j, 2j+1) of row r_rel.
// needs s_in[r][2j+1 .. 2j+8]; read as 5 aligned float2 from col 2j.
#define HFILT(RR, LO, HI) do {                                               \
    const float2* _p = (const float2*)&s_in[(RR)][2 * j];                    \
    float2 _u0 = _p[0], _u1 = _p[1], _u2 = _p[2], _u3 = _p[3], _u4 = _p[4];  \
    float _w0 = _u0.y, _w1 = _u1.x, _w2 = _u1.y, _w3 = _u2.x;                \
    float _w4 = _u2.y, _w5 = _u3.x, _w6 = _u3.y, _w7 = _u4.x;                \
    (HI).x = h1[0]*_w0 + h1[1]*_w1 + h1[2]*_w2 + h1[3]*_w3                   \
           + h1[4]*_w4 + h1[5]*_w5 + h1[6]*_w6;                              \
    (HI).y = h1[0]*_w1 + h1[1]*_w2 + h1[2]*_w3 + h1[3]*_w4                   \
           + h1[4]*_w5 + h1[5]*_w6 + h1[6]*_w7;                              \
    (LO).x = h0[0]*_w1 + h0[1]*_w2 + h0[2]*_w3 + h0[3]*_w4 + h0[4]*_w5;      \
    (LO).y = h0[0]*_w2 + h0[1]*_w3 + h0[2]*_w4 + h0[3]*_w5 + h0[4]*_w6;      \
} while (0)

__global__ __launch_bounds__(256)
void scat_kernel(const float* __restrict__ x,
                 const float* __restrict__ gh0,
                 const float* __restrict__ gh1,
                 float* __restrict__ out)
{
    __shared__ float s_in[INH][INS];    // 20160 B

    const int tid = threadIdx.x;
    const int tx  = blockIdx.x;         // 0..7
    const int ty  = blockIdx.y;         // 0..7
    const int img = blockIdx.z;         // 0..95
    const int b   = img / 3;
    const int ch  = img - 3 * b;

    float h0[5], h1[7];
#pragma unroll
    for (int k = 0; k < 5; ++k) h0[k] = gh0[k];
#pragma unroll
    for (int k = 0; k < 7; ++k) h1[k] = gh1[k];

    const float* xin = x + (size_t)img * (IMG * IMG);
    const int row0 = ty * 64 - 3;
    const int col0 = tx * 64 - 4;

    const bool colsInt = (col0 >= 0) && (col0 + INW <= IMG);
    const bool rowsInt = (row0 >= 0) && (row0 + INH <= IMG);

    // ---- phase 1: tile load ----
    if (colsInt) {
        if (rowsInt) {
            for (int idx = tid; idx < INH * (INS / 4); idx += 256) {
                int r  = idx / 18;
                int c4 = (idx - r * 18) * 4;
                const float4 v = *(const float4*)&xin[(row0 + r) * IMG + col0 + c4];
                *(float4*)&s_in[r][c4] = v;
            }
        } else {
            for (int idx = tid; idx < INH * (INS / 4); idx += 256) {
                int r  = idx / 18;
                int c4 = (idx - r * 18) * 4;
                int gr = row0 + r;
                gr = (gr < 0) ? (-gr - 1) : ((gr >= IMG) ? (2 * IMG - 1 - gr) : gr);
                const float4 v = *(const float4*)&xin[gr * IMG + col0 + c4];
                *(float4*)&s_in[r][c4] = v;
            }
        }
    } else {
        for (int idx = tid; idx < INH * INW; idx += 256) {
            int r = idx / INW;
            int c = idx - r * INW;
            int gr = row0 + r;
            gr = (gr < 0) ? (-gr - 1) : ((gr >= IMG) ? (2 * IMG - 1 - gr) : gr);
            int gc = col0 + c;
            gc = (gc < 0) ? (-gc - 1) : ((gc >= IMG) ? (2 * IMG - 1 - gc) : gc);
            s_in[r][c] = xin[gr * IMG + gc];
        }
    }
    __syncthreads();

    // ---- phase 2: sliding-window vertical + q2c + mag ----
    const int j  = tid & 31;            // output col in tile
    const int tr = tid >> 5;            // 0..7 -> output rows tr*4 .. tr*4+3
    const int rbase = 8 * tr;           // first input row (rel) of window

    float2 wlo[8], whi[8];
#pragma unroll
    for (int t = 0; t < 6; ++t) HFILT(rbase + t, wlo[t], whi[t]);

    const size_t P = (size_t)OUTD * OUTD;
    const size_t obase = ((size_t)b * 21 + ch) * P;
    const int gj = tx * TOW + j;

#pragma unroll
    for (int q = 0; q < 4; ++q) {
        HFILT(rbase + 2 * q + 6, wlo[6], whi[6]);
        HFILT(rbase + 2 * q + 7, wlo[7], whi[7]);

        // vertical filters (float2 lanes = quad cols 2j, 2j+1)
        float2 lhA = {0.f, 0.f}, lhB = {0.f, 0.f};
        float2 hhA = {0.f, 0.f}, hhB = {0.f, 0.f};
#pragma unroll
        for (int k = 0; k < 7; ++k) {
            lhA.x += h1[k] * wlo[k].x;     lhA.y += h1[k] * wlo[k].y;
            lhB.x += h1[k] * wlo[k + 1].x; lhB.y += h1[k] * wlo[k + 1].y;
            hhA.x += h1[k] * whi[k].x;     hhA.y += h1[k] * whi[k].y;
            hhB.x += h1[k] * whi[k + 1].x; hhB.y += h1[k] * whi[k + 1].y;
        }
        float2 llA = {0.f, 0.f}, llB = {0.f, 0.f};
        float2 hlA = {0.f, 0.f}, hlB = {0.f, 0.f};
#pragma unroll
        for (int k = 0; k < 5; ++k) {
            llA.x += h0[k] * wlo[k + 1].x; llA.y += h0[k] * wlo[k + 1].y;
            llB.x += h0[k] * wlo[k + 2].x; llB.y += h0[k] * wlo[k + 2].y;
            hlA.x += h0[k] * whi[k + 1].x; hlA.y += h0[k] * whi[k + 1].y;
            hlB.x += h0[k] * whi[k + 2].x; hlB.y += h0[k] * whi[k + 2].y;
        }

        const int gi = ty * TOH + tr * 4 + q;
        const size_t pix = (size_t)gi * OUTD + gj;
        float* o = out + obase + pix;

        // ll: 2x2 average
        o[0] = 0.25f * (llA.x + llA.y + llB.x + llB.y);

        // q2c (1/sqrt2 scaling folded into magnitude as 0.5 factor):
        // band1 (r,i)=(a-d, b+c)  band2 (a+d, b-c); a=A.x b=A.y c=B.x d=B.y
        {   // lh -> d15 (s=1), d165 (s=6)
            float r1 = lhA.x - lhB.y, i1 = lhA.y + lhB.x;
            float r2 = lhA.x + lhB.y, i2 = lhA.y - lhB.x;
            o[3 * P]  = sqrtf(fmaf(0.5f, r1 * r1 + i1 * i1, MB2)) - MAGBIAS;
            o[18 * P] = sqrtf(fmaf(0.5f, r2 * r2 + i2 * i2, MB2)) - MAGBIAS;
        }
        {   // hh -> d45 (s=2), d135 (s=5)
            float r1 = hhA.x - hhB.y, i1 = hhA.y + hhB.x;
            float r2 = hhA.x + hhB.y, i2 = hhA.y - hhB.x;
            o[6 * P]  = sqrtf(fmaf(0.5f, r1 * r1 + i1 * i1, MB2)) - MAGBIAS;
            o[15 * P] = sqrtf(fmaf(0.5f, r2 * r2 + i2 * i2, MB2)) - MAGBIAS;
        }
        {   // hl -> d75 (s=3), d105 (s=4)
            float r1 = hlA.x - hlB.y, i1 = hlA.y + hlB.x;
            float r2 = hlA.x + hlB.y, i2 = hlA.y - hlB.x;
            o[9 * P]  = sqrtf(fmaf(0.5f, r1 * r1 + i1 * i1, MB2)) - MAGBIAS;
            o[12 * P] = sqrtf(fmaf(0.5f, r2 * r2 + i2 * i2, MB2)) - MAGBIAS;
        }

        // slide window down 2 input rows
#pragma unroll
        for (int t = 0; t < 6; ++t) { wlo[t] = wlo[t + 2]; whi[t] = whi[t + 2]; }
    }
}

extern "C" void kernel_launch(void* const* d_in, const int* in_sizes, int n_in,
                              void* d_out, int out_size, void* d_ws, size_t ws_size,
                              hipStream_t stream) {
    const float* x  = (const float*)d_in[0];
    const float* h0 = (const float*)d_in[1];
    const float* h1 = (const float*)d_in[2];
    float* out = (float*)d_out;

    dim3 grid(IMG / 64, IMG / 64, 32 * 3);   // (8, 8, 96)
    dim3 block(256);
    hipLaunchKernelGGL(scat_kernel, grid, block, 0, stream, x, h0, h1, out);
}

// Round 3
// 267.442 us; speedup vs baseline: 1.1649x; 1.0174x over previous
//
#include <hip/hip_runtime.h>
#include <math.h>

// ScatLayer fused DTCWT scattering: x(32,3,512,512)f32 -> Z(32,21,256,256)f32.
// R3: deeper per-thread strip (8 output rows -> HFILT redundancy 1.375x),
// raw v_sqrt_f32 for magnitudes, vectorized edge-column loads.
// Tile: 32 wide x 64 tall outputs (64x128 input core), halo 4L/3R/3T/3B.
// 256 threads = 32 cols x 8 row-threads; each thread 1 col x 8 output rows,
// 8-row register window sliding by 2.

#define IMG   512
#define OUTD  256
#define TOW   32
#define TOH   64
#define INW   72            // stride & loaded cols; col0 = tx*64 - 4 (16B-aligned)
#define INH   134           // 128 core + 6 halo; row0 = ty*128 - 3
#define INS   72

#define MAGBIAS 0.01f
#define MB2     (MAGBIAS*MAGBIAS)

#define FSQRT(X) __builtin_amdgcn_sqrtf(X)

// horizontal filters at core cols (2j, 2j+1) of tile row RR.
// reads s_in[RR][2j .. 2j+9] as 5 aligned float2.
#define HFILT(RR, LO, HI) do {                                               \
    const float2* _p = (const float2*)&s_in[(RR)][2 * j];                    \
    float2 _u0 = _p[0], _u1 = _p[1], _u2 = _p[2], _u3 = _p[3], _u4 = _p[4];  \
    float _w0 = _u0.y, _w1 = _u1.x, _w2 = _u1.y, _w3 = _u2.x;                \
    float _w4 = _u2.y, _w5 = _u3.x, _w6 = _u3.y, _w7 = _u4.x;                \
    (HI).x = h1[0]*_w0 + h1[1]*_w1 + h1[2]*_w2 + h1[3]*_w3                   \
           + h1[4]*_w4 + h1[5]*_w5 + h1[6]*_w6;                              \
    (HI).y = h1[0]*_w1 + h1[1]*_w2 + h1[2]*_w3 + h1[3]*_w4                   \
           + h1[4]*_w5 + h1[5]*_w6 + h1[6]*_w7;                              \
    (LO).x = h0[0]*_w1 + h0[1]*_w2 + h0[2]*_w3 + h0[3]*_w4 + h0[4]*_w5;      \
    (LO).y = h0[0]*_w2 + h0[1]*_w3 + h0[2]*_w4 + h0[3]*_w5 + h0[4]*_w6;      \
} while (0)

__global__ __launch_bounds__(256)
void scat_kernel(const float* __restrict__ x,
                 const float* __restrict__ gh0,
                 const float* __restrict__ gh1,
                 float* __restrict__ out)
{
    __shared__ float s_in[INH][INS];    // 38592 B -> 4 blocks/CU

    const int tid = threadIdx.x;
    const int tx  = blockIdx.x;         // 0..7
    const int ty  = blockIdx.y;         // 0..3
    const int img = blockIdx.z;         // 0..95
    const int b   = img / 3;
    const int ch  = img - 3 * b;

    float h0[5], h1[7];
#pragma unroll
    for (int k = 0; k < 5; ++k) h0[k] = gh0[k];
#pragma unroll
    for (int k = 0; k < 7; ++k) h1[k] = gh1[k];

    const float* xin = x + (size_t)img * (IMG * IMG);
    const int row0 = ty * 128 - 3;
    const int col0 = tx * 64 - 4;
    const bool colsInt = (col0 >= 0) && (col0 + INW <= IMG);

    // ---- phase 1: tile load (rows always reflect-in-index) ----
    if (colsInt) {
        // all 18 float4 groups are interior columns
        for (int idx = tid; idx < INH * 18; idx += 256) {
            int r  = idx / 18;
            int c4 = (idx - r * 18) * 4;
            int gr = row0 + r;
            gr = (gr < 0) ? (-gr - 1) : ((gr >= IMG) ? (2 * IMG - 1 - gr) : gr);
            *(float4*)&s_in[r][c4] = *(const float4*)&xin[gr * IMG + col0 + c4];
        }
    } else {
        // middle 16 groups (cols 4..67) are interior for every tx
        for (int idx = tid; idx < INH * 16; idx += 256) {
            int r  = idx / 16;
            int c4 = 4 + (idx - r * 16) * 4;
            int gr = row0 + r;
            gr = (gr < 0) ? (-gr - 1) : ((gr >= IMG) ? (2 * IMG - 1 - gr) : gr);
            *(float4*)&s_in[r][c4] = *(const float4*)&xin[gr * IMG + col0 + c4];
        }
        // 8 edge cols {0..3, 68..71} scalar with column reflect
        for (int idx = tid; idx < INH * 8; idx += 256) {
            int r = idx >> 3;
            int e = idx & 7;
            int c = (e < 4) ? e : (64 + e);
            int gr = row0 + r;
            gr = (gr < 0) ? (-gr - 1) : ((gr >= IMG) ? (2 * IMG - 1 - gr) : gr);
            int gc = col0 + c;
            gc = (gc < 0) ? (-gc - 1) : ((gc >= IMG) ? (2 * IMG - 1 - gc) : gc);
            s_in[r][c] = xin[gr * IMG + gc];
        }
    }
    __syncthreads();

    // ---- phase 2: sliding-window vertical + q2c + mag ----
    const int j  = tid & 31;            // output col in tile
    const int tr = tid >> 5;            // 0..7 -> output rows tr*8 .. tr*8+7
    const int rbase = 16 * tr;          // first tile input row of window

    float2 wlo[8], whi[8];
#pragma unroll
    for (int t = 0; t < 6; ++t) HFILT(rbase + t, wlo[t], whi[t]);

    const size_t P = (size_t)OUTD * OUTD;
    const size_t obase = ((size_t)b * 21 + ch) * P;
    const int gj = tx * TOW + j;

#pragma unroll
    for (int q = 0; q < 8; ++q) {
        HFILT(rbase + 2 * q + 6, wlo[6], whi[6]);
        HFILT(rbase + 2 * q + 7, wlo[7], whi[7]);

        float2 lhA = {0.f, 0.f}, lhB = {0.f, 0.f};
        float2 hhA = {0.f, 0.f}, hhB = {0.f, 0.f};
#pragma unroll
        for (int k = 0; k < 7; ++k) {
            lhA.x += h1[k] * wlo[k].x;     lhA.y += h1[k] * wlo[k].y;
            lhB.x += h1[k] * wlo[k + 1].x; lhB.y += h1[k] * wlo[k + 1].y;
            hhA.x += h1[k] * whi[k].x;     hhA.y += h1[k] * whi[k].y;
            hhB.x += h1[k] * whi[k + 1].x; hhB.y += h1[k] * whi[k + 1].y;
        }
        float2 llA = {0.f, 0.f}, llB = {0.f, 0.f};
        float2 hlA = {0.f, 0.f}, hlB = {0.f, 0.f};
#pragma unroll
        for (int k = 0; k < 5; ++k) {
            llA.x += h0[k] * wlo[k + 1].x; llA.y += h0[k] * wlo[k + 1].y;
            llB.x += h0[k] * wlo[k + 2].x; llB.y += h0[k] * wlo[k + 2].y;
            hlA.x += h0[k] * whi[k + 1].x; hlA.y += h0[k] * whi[k + 1].y;
            hlB.x += h0[k] * whi[k + 2].x; hlB.y += h0[k] * whi[k + 2].y;
        }

        const int gi = ty * TOH + tr * 8 + q;
        float* o = out + obase + (size_t)gi * OUTD + gj;

        // s=0: ll 2x2 average
        o[0] = 0.25f * (llA.x + llA.y + llB.x + llB.y);

        // q2c (1/sqrt2 folded into magnitude as 0.5 factor):
        // band1 (a-d, b+c)  band2 (a+d, b-c); a=A.x b=A.y c=B.x d=B.y
        {   // lh -> d15 (s=1), d165 (s=6)
            float r1 = lhA.x - lhB.y, i1 = lhA.y + lhB.x;
            float r2 = lhA.x + lhB.y, i2 = lhA.y - lhB.x;
            o[3 * P]  = FSQRT(fmaf(0.5f, r1 * r1 + i1 * i1, MB2)) - MAGBIAS;
            o[18 * P] = FSQRT(fmaf(0.5f, r2 * r2 + i2 * i2, MB2)) - MAGBIAS;
        }
        {   // hh -> d45 (s=2), d135 (s=5)
            float r1 = hhA.x - hhB.y, i1 = hhA.y + hhB.x;
            float r2 = hhA.x + hhB.y, i2 = hhA.y - hhB.x;
            o[6 * P]  = FSQRT(fmaf(0.5f, r1 * r1 + i1 * i1, MB2)) - MAGBIAS;
            o[15 * P] = FSQRT(fmaf(0.5f, r2 * r2 + i2 * i2, MB2)) - MAGBIAS;
        }
        {   // hl -> d75 (s=3), d105 (s=4)
            float r1 = hlA.x - hlB.y, i1 = hlA.y + hlB.x;
            float r2 = hlA.x + hlB.y, i2 = hlA.y - hlB.x;
            o[9 * P]  = FSQRT(fmaf(0.5f, r1 * r1 + i1 * i1, MB2)) - MAGBIAS;
            o[12 * P] = FSQRT(fmaf(0.5f, r2 * r2 + i2 * i2, MB2)) - MAGBIAS;
        }

        // slide window down 2 input rows
#pragma unroll
        for (int t = 0; t < 6; ++t) { wlo[t] = wlo[t + 2]; whi[t] = whi[t + 2]; }
    }
}

extern "C" void kernel_launch(void* const* d_in, const int* in_sizes, int n_in,
                              void* d_out, int out_size, void* d_ws, size_t ws_size,
                              hipStream_t stream) {
    const float* x  = (const float*)d_in[0];
    const float* h0 = (const float*)d_in[1];
    const float* h1 = (const float*)d_in[2];
    float* out = (float*)d_out;

    dim3 grid(IMG / 64, IMG / 128, 32 * 3);   // (8, 4, 96)
    dim3 block(256);
    hipLaunchKernelGGL(scat_kernel, grid, block, 0, stream, x, h0, h1, out);
}